// Round 4
// baseline (1968.663 us; speedup 1.0000x reference)
//
#include <hip/hip_runtime.h>

#define B_ 16
#define NF_ 16
#define N_ 1024
#define D_ 128
#define S_ 8
#define SCALE_ 0.08838834764831845f
#define NB 256
#define NT 512

struct SmemA {
  float Xt[64 * 129];       // normalized in place
  float qWs[1024];
  float at[512];
  float rowsum[64], rowsum2[64];
  float qbs[8];
};
struct SmemB {
  float Pk[1024], upd[1024], hn[1024], buf[1024], hid[1024], qsh[1024];
  float gi[3072], gh[3072];
  float mst[8], ist[8], ssm[8];
};
union Smem { SmemA a; SmemB b; };

__device__ __forceinline__ void grid_sync(unsigned* cnt, unsigned epoch) {
  __syncthreads();
  if (threadIdx.x == 0) {
    __threadfence();  // release: write back L2 so other XCDs can see our stores
    __hip_atomic_fetch_add(cnt, 1u, __ATOMIC_RELAXED, __HIP_MEMORY_SCOPE_AGENT);
    unsigned target = NB * epoch;
    while (__hip_atomic_load(cnt, __ATOMIC_RELAXED, __HIP_MEMORY_SCOPE_AGENT) < target)
      __builtin_amdgcn_s_sleep(1);
    __threadfence();  // acquire: invalidate L1/L2 so we see other XCDs' stores
  }
  __syncthreads();
}

// per-slot mean/rsqrt over arr[s*128 + i]; wave w handles slot w. All 512 threads call.
__device__ __forceinline__ void stats8(const float* arr, float* mst, float* ist, float eps) {
  __syncthreads();
  int w = threadIdx.x >> 6, lane = threadIdx.x & 63;
  float v0 = arr[w * 128 + lane], v1 = arr[w * 128 + 64 + lane];
  float s1 = v0 + v1, s2 = v0 * v0 + v1 * v1;
#pragma unroll
  for (int off = 32; off; off >>= 1) { s1 += __shfl_down(s1, off); s2 += __shfl_down(s2, off); }
  if (lane == 0) {
    float m = s1 * (1.f / 128.f);
    float var = s2 * (1.f / 128.f) - m * m;
    mst[w] = m; ist[w] = rsqrtf(var + eps);
  }
  __syncthreads();
}

// acc[s] += Wrow . v[s][:] for 8 slot-vectors (LDS, stride 128); out[s*384+o]
__device__ __forceinline__ void dorow8(const float* __restrict__ wrow, float bias,
                                       const float* v, float* out, int o) {
  float acc[8];
#pragma unroll
  for (int s = 0; s < 8; ++s) acc[s] = bias;
  const float4* wr = (const float4*)wrow;
#pragma unroll 8
  for (int i = 0; i < 32; ++i) {
    float4 wv = wr[i];
#pragma unroll
    for (int s = 0; s < 8; ++s) {
      float4 xv = *(const float4*)(v + s * 128 + i * 4);
      acc[s] += wv.x * xv.x + wv.y * xv.y + wv.z * xv.z + wv.w * xv.w;
    }
  }
#pragma unroll
  for (int s = 0; s < 8; ++s) out[s * 384 + o] = acc[s];
}

__device__ __forceinline__ float sigm(float x) { return 1.f / (1.f + __expf(-x)); }
__device__ __forceinline__ float tanh_f(float x) { return 1.f - 2.f / (1.f + __expf(2.f * x)); }

// LN_sl(slot_sh) -> q -> qW = q@Wk, qb = q.bk (global). All 512 threads.
__device__ void slots_to_q(SmemB& B, const float* slot_sh,
    const float* g_sl, const float* be_sl, const float* Wq, const float* bq,
    const float* Wk, const float* bk, float* qW_g, float* qb_g, int b) {
  int t = threadIdx.x, k = t & 127, sp = t >> 7;  // sp in 0..3 -> slots {sp, sp+4}
  stats8(slot_sh, B.mst, B.ist, 1e-5f);
  if (t < 128) {
    float g = g_sl[t], be = be_sl[t];
#pragma unroll
    for (int s = 0; s < 8; ++s)
      B.buf[s * 128 + t] = (slot_sh[s * 128 + t] - B.mst[s]) * B.ist[s] * g + be;
  }
  __syncthreads();
  {
    float a0 = bq[k], a1 = bq[k];
    const float4* wr = (const float4*)(Wq + k * 128);
#pragma unroll 8
    for (int i = 0; i < 32; ++i) {
      float4 wv = wr[i];
      float4 x0 = *(const float4*)(B.buf + sp * 128 + i * 4);
      float4 x1 = *(const float4*)(B.buf + (sp + 4) * 128 + i * 4);
      a0 += wv.x * x0.x + wv.y * x0.y + wv.z * x0.z + wv.w * x0.w;
      a1 += wv.x * x1.x + wv.y * x1.y + wv.z * x1.z + wv.w * x1.w;
    }
    B.qsh[sp * 128 + k] = a0; B.qsh[(sp + 4) * 128 + k] = a1;
  }
  __syncthreads();
  {
    float a0 = 0.f, a1 = 0.f;
#pragma unroll 16
    for (int d = 0; d < 128; ++d) {
      float wv = Wk[d * 128 + k];
      a0 += B.qsh[sp * 128 + d] * wv;
      a1 += B.qsh[(sp + 4) * 128 + d] * wv;
    }
    qW_g[(b * 8 + sp) * 128 + k] = a0;
    qW_g[(b * 8 + sp + 4) * 128 + k] = a1;
  }
  if (t < 128) {
    float bkt = bk[t];
#pragma unroll
    for (int s = 0; s < 8; ++s) B.hid[s * 128 + t] = B.qsh[s * 128 + t] * bkt;
  }
  __syncthreads();
  {
    int w = t >> 6, lane = t & 63;
    float s1 = B.hid[w * 128 + lane] + B.hid[w * 128 + 64 + lane];
#pragma unroll
    for (int off = 32; off; off >>= 1) s1 += __shfl_down(s1, off);
    if (lane == 0) qb_g[b * 8 + w] = s1;
  }
}

__global__ __launch_bounds__(NT) void slot_persist(
    const float* __restrict__ x, const float* __restrict__ slots_init,
    const float* __restrict__ Wq, const float* __restrict__ bq,
    const float* __restrict__ Wk, const float* __restrict__ bk,
    const float* __restrict__ Wv, const float* __restrict__ bv,
    const float* __restrict__ W1, const float* __restrict__ b1,
    const float* __restrict__ W2, const float* __restrict__ b2,
    const float* __restrict__ Wih, const float* __restrict__ Whh,
    const float* __restrict__ bih, const float* __restrict__ bhh,
    const float* __restrict__ g_in, const float* __restrict__ be_in,
    const float* __restrict__ g_sl, const float* __restrict__ be_sl,
    const float* __restrict__ g_ff, const float* __restrict__ be_ff,
    float* out_slots, float* out_attn,
    unsigned* cnt, float* qW_g, float* qb_g, float* P_part, float* S_part) {
  __shared__ __align__(16) Smem sm;
  __shared__ __align__(16) float slot_sh[1024];
  __shared__ float gs[128], bs_[128];
  int t = threadIdx.x, bid = blockIdx.x;
  int b_a = bid >> 4, jt = bid & 15;

  if (t < 128) { gs[t] = g_in[t]; bs_[t] = be_in[t]; }
  if (bid < 16) {
    if (t < 128) {
#pragma unroll
      for (int s = 0; s < 8; ++s) slot_sh[s * 128 + t] = slots_init[s * 128 + t];
    }
    slots_to_q(sm.b, slot_sh, g_sl, be_sl, Wq, bq, Wk, bk, qW_g, qb_g, bid);
  }
  float4 pf[4];
  {
    const float* xsrc = x + (((long)b_a * NF_ + 0) * N_ + jt * 64) * D_;
#pragma unroll
    for (int i = 0; i < 4; ++i) {
      int ch = t + i * 512;
      pf[i] = *(const float4*)(xsrc + (ch >> 5) * 128 + (ch & 31) * 4);
    }
  }
  grid_sync(cnt, 1);

  for (int it = 0; it < 17; ++it) {
    int f = (it == 0) ? 0 : it - 1;
    int wo = it > 0;
    // ================= phase A =================
#pragma unroll
    for (int i = 0; i < 4; ++i) {
      int ch = t + i * 512;
      float* dst = sm.a.Xt + (ch >> 5) * 129 + (ch & 31) * 4;
      dst[0] = pf[i].x; dst[1] = pf[i].y; dst[2] = pf[i].z; dst[3] = pf[i].w;
    }
    sm.a.qWs[t] = qW_g[b_a * 1024 + t];
    sm.a.qWs[512 + t] = qW_g[b_a * 1024 + 512 + t];
    if (t < 8) sm.a.qbs[t] = qb_g[b_a * 8 + t];
    __syncthreads();
    int r8 = t >> 3, p8 = t & 7;
    {
      const float* row = sm.a.Xt + r8 * 129 + p8 * 16;
      float s1 = 0.f, s2 = 0.f;
#pragma unroll
      for (int i = 0; i < 16; ++i) { float v = row[i]; s1 += v; s2 += v * v; }
      s1 += __shfl_down(s1, 1); s2 += __shfl_down(s2, 1);
      s1 += __shfl_down(s1, 2); s2 += __shfl_down(s2, 2);
      s1 += __shfl_down(s1, 4); s2 += __shfl_down(s2, 4);
      if (p8 == 0) { sm.a.rowsum[r8] = s1; sm.a.rowsum2[r8] = s2; }
    }
    __syncthreads();
    {
      float m = sm.a.rowsum[r8] * (1.f / 128.f);
      float var = sm.a.rowsum2[r8] * (1.f / 128.f) - m * m;
      float inv = rsqrtf(var + 1e-5f);
      float* row = sm.a.Xt + r8 * 129 + p8 * 16;
      const float* gg = gs + p8 * 16;
      const float* bb = bs_ + p8 * 16;
#pragma unroll
      for (int i = 0; i < 16; ++i) row[i] = (row[i] - m) * inv * gg[i] + bb[i];
    }
    __syncthreads();
    {
      int s = t >> 6, j = t & 63;
      const float* qq = sm.a.qWs + s * 128;
      const float* xr = sm.a.Xt + j * 129;
      float d = 0.f;
#pragma unroll
      for (int k = 0; k < 128; ++k) d += xr[k] * qq[k];
      sm.a.at[s * 64 + j] = (d + sm.a.qbs[s]) * SCALE_;
    }
    __syncthreads();
    if (t < 64) {
      float vals[8], mx = -1e30f;
#pragma unroll
      for (int s = 0; s < 8; ++s) { vals[s] = sm.a.at[s * 64 + t]; mx = fmaxf(mx, vals[s]); }
      float sum = 0.f;
#pragma unroll
      for (int s = 0; s < 8; ++s) { vals[s] = __expf(vals[s] - mx); sum += vals[s]; }
      float rr = 1.f / sum;
#pragma unroll
      for (int s = 0; s < 8; ++s) { vals[s] = vals[s] * rr + 1e-8f; sm.a.at[s * 64 + t] = vals[s]; }
      if (wo) {
#pragma unroll
        for (int s = 0; s < 8; ++s)
          out_attn[(((long)b_a * NF_ + f) * S_ + s) * N_ + jt * 64 + t] = vals[s];
      }
    }
    __syncthreads();
    {
      int w = t >> 6, lane = t & 63;
      float v = sm.a.at[w * 64 + lane];
#pragma unroll
      for (int off = 32; off; off >>= 1) v += __shfl_down(v, off);
      if (lane == 0) S_part[(b_a * 16 + jt) * 8 + w] = v;
    }
    {
      int k2 = t & 127, h = t >> 7;
      float u0 = 0.f, u1 = 0.f;
      const float* a0 = sm.a.at + h * 64;
      const float* a1 = sm.a.at + (h + 4) * 64;
#pragma unroll 8
      for (int j = 0; j < 64; ++j) {
        float xv = sm.a.Xt[j * 129 + k2];
        u0 += xv * a0[j]; u1 += xv * a1[j];
      }
      float* pp = P_part + (long)(b_a * 16 + jt) * 8 * 128;
      pp[h * 128 + k2] = u0;
      pp[(h + 4) * 128 + k2] = u1;
    }
    grid_sync(cnt, 2 + 2 * it);
    // ================= phase B =================
    if (it < 16) {  // prefetch next frame tile (f(it+1) == it)
      const float* xsrc = x + (((long)b_a * NF_ + it) * N_ + jt * 64) * D_;
#pragma unroll
      for (int i = 0; i < 4; ++i) {
        int ch = t + i * 512;
        pf[i] = *(const float4*)(xsrc + (ch >> 5) * 128 + (ch & 31) * 4);
      }
    }
    if (bid < 16) {
      int b = bid, k = t & 127, sp = t >> 7;
      SmemB& B = sm.b;
      float pa0 = 0.f, pa1 = 0.f;
#pragma unroll
      for (int j = 0; j < 16; ++j) {
        const float* pp = P_part + (long)(b * 16 + j) * 8 * 128;
        pa0 += pp[sp * 128 + k];
        pa1 += pp[(sp + 4) * 128 + k];
      }
      if (t < 8) {
        float ss = 0.f;
#pragma unroll
        for (int j = 0; j < 16; ++j) ss += S_part[(b * 16 + j) * 8 + t];
        B.ssm[t] = ss;
      }
      __syncthreads();
      B.Pk[sp * 128 + k] = pa0 / B.ssm[sp];
      B.Pk[(sp + 4) * 128 + k] = pa1 / B.ssm[sp + 4];
      __syncthreads();
      {  // upd = Wv @ Pk + bv
        float a0 = bv[k], a1 = bv[k];
        const float4* wr = (const float4*)(Wv + k * 128);
#pragma unroll 8
        for (int i = 0; i < 32; ++i) {
          float4 wv = wr[i];
          float4 x0 = *(const float4*)(B.Pk + sp * 128 + i * 4);
          float4 x1 = *(const float4*)(B.Pk + (sp + 4) * 128 + i * 4);
          a0 += wv.x * x0.x + wv.y * x0.y + wv.z * x0.z + wv.w * x0.w;
          a1 += wv.x * x1.x + wv.y * x1.y + wv.z * x1.z + wv.w * x1.w;
        }
        B.upd[sp * 128 + k] = a0; B.upd[(sp + 4) * 128 + k] = a1;
      }
      __syncthreads();
      if (t < 384) dorow8(Wih + t * 128, bih[t], B.upd, B.gi, t);
      {
        int rh = (t >= 384) ? (t - 384) : (t < 256 ? 128 + t : -1);
        if (rh >= 0) dorow8(Whh + rh * 128, bhh[rh], slot_sh, B.gh, rh);
      }
      __syncthreads();
      if (t < 128) {
#pragma unroll
        for (int s = 0; s < 8; ++s) {
          float r = sigm(B.gi[s * 384 + t] + B.gh[s * 384 + t]);
          float z = sigm(B.gi[s * 384 + 128 + t] + B.gh[s * 384 + 128 + t]);
          float n = tanh_f(B.gi[s * 384 + 256 + t] + r * B.gh[s * 384 + 256 + t]);
          B.hn[s * 128 + t] = (1.f - z) * n + z * slot_sh[s * 128 + t];
        }
      }
      stats8(B.hn, B.mst, B.ist, 1e-5f);
      if (t < 128) {
        float g = g_ff[t], be = be_ff[t];
#pragma unroll
        for (int s = 0; s < 8; ++s)
          B.buf[s * 128 + t] = (B.hn[s * 128 + t] - B.mst[s]) * B.ist[s] * g + be;
      }
      __syncthreads();
      {  // hid = relu(W1 @ buf + b1)
        float a0 = b1[k], a1 = b1[k];
        const float4* wr = (const float4*)(W1 + k * 128);
#pragma unroll 8
        for (int i = 0; i < 32; ++i) {
          float4 wv = wr[i];
          float4 x0 = *(const float4*)(B.buf + sp * 128 + i * 4);
          float4 x1 = *(const float4*)(B.buf + (sp + 4) * 128 + i * 4);
          a0 += wv.x * x0.x + wv.y * x0.y + wv.z * x0.z + wv.w * x0.w;
          a1 += wv.x * x1.x + wv.y * x1.y + wv.z * x1.z + wv.w * x1.w;
        }
        B.hid[sp * 128 + k] = fmaxf(a0, 0.f);
        B.hid[(sp + 4) * 128 + k] = fmaxf(a1, 0.f);
      }
      __syncthreads();
      {  // sn = hn + W2 @ hid + b2 -> slot_sh, out_slots
        float a0 = b2[k], a1 = b2[k];
        const float4* wr = (const float4*)(W2 + k * 128);
#pragma unroll 8
        for (int i = 0; i < 32; ++i) {
          float4 wv = wr[i];
          float4 x0 = *(const float4*)(B.hid + sp * 128 + i * 4);
          float4 x1 = *(const float4*)(B.hid + (sp + 4) * 128 + i * 4);
          a0 += wv.x * x0.x + wv.y * x0.y + wv.z * x0.z + wv.w * x0.w;
          a1 += wv.x * x1.x + wv.y * x1.y + wv.z * x1.z + wv.w * x1.w;
        }
        float sn0 = B.hn[sp * 128 + k] + a0;
        float sn1 = B.hn[(sp + 4) * 128 + k] + a1;
        slot_sh[sp * 128 + k] = sn0;
        slot_sh[(sp + 4) * 128 + k] = sn1;
        if (wo) {
          out_slots[(((long)b * NF_ + f) * S_ + sp) * D_ + k] = sn0;
          out_slots[(((long)b * NF_ + f) * S_ + sp + 4) * D_ + k] = sn1;
        }
      }
      if (it < 16)
        slots_to_q(B, slot_sh, g_sl, be_sl, Wq, bq, Wk, bk, qW_g, qb_g, b);
    }
    if (it < 16) grid_sync(cnt, 3 + 2 * it);
  }
}

extern "C" void kernel_launch(void* const* d_in, const int* in_sizes, int n_in,
                              void* d_out, int out_size, void* d_ws, size_t ws_size,
                              hipStream_t stream) {
  const float* inputs     = (const float*)d_in[0];
  const float* slots_init = (const float*)d_in[1];
  const float* Wq  = (const float*)d_in[2];
  const float* bq  = (const float*)d_in[3];
  const float* Wk  = (const float*)d_in[4];
  const float* bk  = (const float*)d_in[5];
  const float* Wv  = (const float*)d_in[6];
  const float* bv  = (const float*)d_in[7];
  const float* W1  = (const float*)d_in[8];
  const float* b1  = (const float*)d_in[9];
  const float* W2  = (const float*)d_in[10];
  const float* b2  = (const float*)d_in[11];
  const float* Wih = (const float*)d_in[12];
  const float* Whh = (const float*)d_in[13];
  const float* bih = (const float*)d_in[14];
  const float* bhh = (const float*)d_in[15];
  const float* g_in  = (const float*)d_in[16];
  const float* be_in = (const float*)d_in[17];
  const float* g_sl  = (const float*)d_in[18];
  const float* be_sl = (const float*)d_in[19];
  const float* g_ff  = (const float*)d_in[20];
  const float* be_ff = (const float*)d_in[21];

  float* out_slots = (float*)d_out;
  float* out_attn  = out_slots + (size_t)B_ * NF_ * S_ * D_;

  char* ws = (char*)d_ws;
  unsigned* cnt  = (unsigned*)ws;                    // 64 B (zeroed below)
  float* qW_g    = (float*)(ws + 1024);              // 64 KB
  float* qb_g    = (float*)(ws + 1024 + 65536);      // 512 B
  float* P_part  = (float*)(ws + 67072);             // 1 MB
  float* S_part  = (float*)(ws + 67072 + 1048576);   // 8 KB

  hipMemsetAsync(d_ws, 0, 256, stream);  // reset barrier counter (graph-capturable)

  slot_persist<<<NB, NT, 0, stream>>>(inputs, slots_init, Wq, bq, Wk, bk, Wv, bv,
      W1, b1, W2, b2, Wih, Whh, bih, bhh, g_in, be_in, g_sl, be_sl, g_ff, be_ff,
      out_slots, out_attn, cnt, qW_g, qb_g, P_part, S_part);
}

// Round 5
// 1408.993 us; speedup vs baseline: 1.3972x; 1.3972x over previous
//
#include <hip/hip_runtime.h>

#define B_ 16
#define NF_ 16
#define N_ 1024
#define D_ 128
#define S_ 8
#define SCALE_ 0.08838834764831845f
#define NB 256
#define NT 512

struct SmemA {
  float Xt[64 * 129];       // normalized in place
  float qWs[1024];
  float at[512];
  float rowsum[64], rowsum2[64];
  float qbs[8];
};
struct SmemB {
  float Pk[1024], upd[1024], hn[1024], buf[1024], hid[1024], qsh[1024];
  float gi[3072], gh[3072];
  float mst[8], ist[8], ssm[8];
};
union Smem { SmemA a; SmemB b; };

// ---- fence-free device-coherent accessors (sc1 ops, no L2 writeback/invalidate) ----
__device__ __forceinline__ float gload(const float* p) {
  return __hip_atomic_load(p, __ATOMIC_RELAXED, __HIP_MEMORY_SCOPE_AGENT);
}
__device__ __forceinline__ void gstore(float* p, float v) {
  __hip_atomic_store(p, v, __ATOMIC_RELAXED, __HIP_MEMORY_SCOPE_AGENT);
}

__device__ __forceinline__ void grid_sync(unsigned* cnt, unsigned epoch) {
  __syncthreads();  // compiler drains vmcnt before s_barrier -> all our sc1 stores are globally visible
  if (threadIdx.x == 0) {
    __builtin_amdgcn_s_waitcnt(0);  // belt & braces: everything drained before arrive
    __atomic_signal_fence(__ATOMIC_ACQ_REL);
    __hip_atomic_fetch_add(cnt, 1u, __ATOMIC_RELAXED, __HIP_MEMORY_SCOPE_AGENT);
    unsigned target = NB * epoch;
    while (__hip_atomic_load(cnt, __ATOMIC_RELAXED, __HIP_MEMORY_SCOPE_AGENT) < target)
      __builtin_amdgcn_s_sleep(4);
    __atomic_signal_fence(__ATOMIC_ACQ_REL);
  }
  __syncthreads();
}

// per-slot mean/rsqrt over arr[s*128 + i]; wave w handles slot w. All 512 threads call.
__device__ __forceinline__ void stats8(const float* arr, float* mst, float* ist, float eps) {
  __syncthreads();
  int w = threadIdx.x >> 6, lane = threadIdx.x & 63;
  float v0 = arr[w * 128 + lane], v1 = arr[w * 128 + 64 + lane];
  float s1 = v0 + v1, s2 = v0 * v0 + v1 * v1;
#pragma unroll
  for (int off = 32; off; off >>= 1) { s1 += __shfl_down(s1, off); s2 += __shfl_down(s2, off); }
  if (lane == 0) {
    float m = s1 * (1.f / 128.f);
    float var = s2 * (1.f / 128.f) - m * m;
    mst[w] = m; ist[w] = rsqrtf(var + eps);
  }
  __syncthreads();
}

// acc[s] += Wrow . v[s][:] for 8 slot-vectors (LDS, stride 128); out[s*384+o]
__device__ __forceinline__ void dorow8(const float* __restrict__ wrow, float bias,
                                       const float* v, float* out, int o) {
  float acc[8];
#pragma unroll
  for (int s = 0; s < 8; ++s) acc[s] = bias;
  const float4* wr = (const float4*)wrow;
#pragma unroll 8
  for (int i = 0; i < 32; ++i) {
    float4 wv = wr[i];
#pragma unroll
    for (int s = 0; s < 8; ++s) {
      float4 xv = *(const float4*)(v + s * 128 + i * 4);
      acc[s] += wv.x * xv.x + wv.y * xv.y + wv.z * xv.z + wv.w * xv.w;
    }
  }
#pragma unroll
  for (int s = 0; s < 8; ++s) out[s * 384 + o] = acc[s];
}

__device__ __forceinline__ float sigm(float x) { return 1.f / (1.f + __expf(-x)); }
__device__ __forceinline__ float tanh_f(float x) { return 1.f - 2.f / (1.f + __expf(2.f * x)); }

// LN_sl(slot_sh) -> q -> qW = q@Wk (sc1 to global), qb = q.bk. All 512 threads.
__device__ void slots_to_q(SmemB& B, const float* slot_sh,
    const float* g_sl, const float* be_sl, const float* Wq, const float* bq,
    const float* Wk, const float* bk, float* qW_g, float* qb_g, int b) {
  int t = threadIdx.x, k = t & 127, sp = t >> 7;  // sp in 0..3 -> slots {sp, sp+4}
  stats8(slot_sh, B.mst, B.ist, 1e-5f);
  if (t < 128) {
    float g = g_sl[t], be = be_sl[t];
#pragma unroll
    for (int s = 0; s < 8; ++s)
      B.buf[s * 128 + t] = (slot_sh[s * 128 + t] - B.mst[s]) * B.ist[s] * g + be;
  }
  __syncthreads();
  {
    float a0 = bq[k], a1 = bq[k];
    const float4* wr = (const float4*)(Wq + k * 128);
#pragma unroll 8
    for (int i = 0; i < 32; ++i) {
      float4 wv = wr[i];
      float4 x0 = *(const float4*)(B.buf + sp * 128 + i * 4);
      float4 x1 = *(const float4*)(B.buf + (sp + 4) * 128 + i * 4);
      a0 += wv.x * x0.x + wv.y * x0.y + wv.z * x0.z + wv.w * x0.w;
      a1 += wv.x * x1.x + wv.y * x1.y + wv.z * x1.z + wv.w * x1.w;
    }
    B.qsh[sp * 128 + k] = a0; B.qsh[(sp + 4) * 128 + k] = a1;
  }
  __syncthreads();
  {
    float a0 = 0.f, a1 = 0.f;
#pragma unroll 16
    for (int d = 0; d < 128; ++d) {
      float wv = Wk[d * 128 + k];
      a0 += B.qsh[sp * 128 + d] * wv;
      a1 += B.qsh[(sp + 4) * 128 + d] * wv;
    }
    gstore(&qW_g[(b * 8 + sp) * 128 + k], a0);
    gstore(&qW_g[(b * 8 + sp + 4) * 128 + k], a1);
  }
  if (t < 128) {
    float bkt = bk[t];
#pragma unroll
    for (int s = 0; s < 8; ++s) B.hid[s * 128 + t] = B.qsh[s * 128 + t] * bkt;
  }
  __syncthreads();
  {
    int w = t >> 6, lane = t & 63;
    float s1 = B.hid[w * 128 + lane] + B.hid[w * 128 + 64 + lane];
#pragma unroll
    for (int off = 32; off; off >>= 1) s1 += __shfl_down(s1, off);
    if (lane == 0) gstore(&qb_g[b * 8 + w], s1);
  }
}

__global__ __launch_bounds__(NT) void slot_persist(
    const float* __restrict__ x, const float* __restrict__ slots_init,
    const float* __restrict__ Wq, const float* __restrict__ bq,
    const float* __restrict__ Wk, const float* __restrict__ bk,
    const float* __restrict__ Wv, const float* __restrict__ bv,
    const float* __restrict__ W1, const float* __restrict__ b1,
    const float* __restrict__ W2, const float* __restrict__ b2,
    const float* __restrict__ Wih, const float* __restrict__ Whh,
    const float* __restrict__ bih, const float* __restrict__ bhh,
    const float* __restrict__ g_in, const float* __restrict__ be_in,
    const float* __restrict__ g_sl, const float* __restrict__ be_sl,
    const float* __restrict__ g_ff, const float* __restrict__ be_ff,
    float* out_slots, float* out_attn,
    unsigned* cnt, float* qW_g, float* qb_g, float* P_part, float* S_part) {
  __shared__ __align__(16) Smem sm;
  __shared__ __align__(16) float slot_sh[1024];
  __shared__ float gs[128], bs_[128];
  int t = threadIdx.x, bid = blockIdx.x;
  int b_a = bid >> 4, jt = bid & 15;

  if (t < 128) { gs[t] = g_in[t]; bs_[t] = be_in[t]; }
  if (bid < 16) {
    if (t < 128) {
#pragma unroll
      for (int s = 0; s < 8; ++s) slot_sh[s * 128 + t] = slots_init[s * 128 + t];
    }
    slots_to_q(sm.b, slot_sh, g_sl, be_sl, Wq, bq, Wk, bk, qW_g, qb_g, bid);
  }
  float4 pf[4];
  {
    const float* xsrc = x + (((long)b_a * NF_ + 0) * N_ + jt * 64) * D_;
#pragma unroll
    for (int i = 0; i < 4; ++i) {
      int ch = t + i * 512;
      pf[i] = *(const float4*)(xsrc + (ch >> 5) * 128 + (ch & 31) * 4);
    }
  }
  grid_sync(cnt, 1);

  for (int it = 0; it < 17; ++it) {
    int f = (it == 0) ? 0 : it - 1;
    int wo = it > 0;
    // ================= phase A =================
#pragma unroll
    for (int i = 0; i < 4; ++i) {
      int ch = t + i * 512;
      float* dst = sm.a.Xt + (ch >> 5) * 129 + (ch & 31) * 4;
      dst[0] = pf[i].x; dst[1] = pf[i].y; dst[2] = pf[i].z; dst[3] = pf[i].w;
    }
    sm.a.qWs[t] = gload(&qW_g[b_a * 1024 + t]);
    sm.a.qWs[512 + t] = gload(&qW_g[b_a * 1024 + 512 + t]);
    if (t < 8) sm.a.qbs[t] = gload(&qb_g[b_a * 8 + t]);
    __syncthreads();
    int r8 = t >> 3, p8 = t & 7;
    {
      const float* row = sm.a.Xt + r8 * 129 + p8 * 16;
      float s1 = 0.f, s2 = 0.f;
#pragma unroll
      for (int i = 0; i < 16; ++i) { float v = row[i]; s1 += v; s2 += v * v; }
      s1 += __shfl_down(s1, 1); s2 += __shfl_down(s2, 1);
      s1 += __shfl_down(s1, 2); s2 += __shfl_down(s2, 2);
      s1 += __shfl_down(s1, 4); s2 += __shfl_down(s2, 4);
      if (p8 == 0) { sm.a.rowsum[r8] = s1; sm.a.rowsum2[r8] = s2; }
    }
    __syncthreads();
    {
      float m = sm.a.rowsum[r8] * (1.f / 128.f);
      float var = sm.a.rowsum2[r8] * (1.f / 128.f) - m * m;
      float inv = rsqrtf(var + 1e-5f);
      float* row = sm.a.Xt + r8 * 129 + p8 * 16;
      const float* gg = gs + p8 * 16;
      const float* bb = bs_ + p8 * 16;
#pragma unroll
      for (int i = 0; i < 16; ++i) row[i] = (row[i] - m) * inv * gg[i] + bb[i];
    }
    __syncthreads();
    {
      int s = t >> 6, j = t & 63;
      const float* qq = sm.a.qWs + s * 128;
      const float* xr = sm.a.Xt + j * 129;
      float d = 0.f;
#pragma unroll
      for (int k = 0; k < 128; ++k) d += xr[k] * qq[k];
      sm.a.at[s * 64 + j] = (d + sm.a.qbs[s]) * SCALE_;
    }
    __syncthreads();
    if (t < 64) {
      float vals[8], mx = -1e30f;
#pragma unroll
      for (int s = 0; s < 8; ++s) { vals[s] = sm.a.at[s * 64 + t]; mx = fmaxf(mx, vals[s]); }
      float sum = 0.f;
#pragma unroll
      for (int s = 0; s < 8; ++s) { vals[s] = __expf(vals[s] - mx); sum += vals[s]; }
      float rr = 1.f / sum;
#pragma unroll
      for (int s = 0; s < 8; ++s) { vals[s] = vals[s] * rr + 1e-8f; sm.a.at[s * 64 + t] = vals[s]; }
      if (wo) {
#pragma unroll
        for (int s = 0; s < 8; ++s)
          out_attn[(((long)b_a * NF_ + f) * S_ + s) * N_ + jt * 64 + t] = vals[s];
      }
    }
    __syncthreads();
    {
      int w = t >> 6, lane = t & 63;
      float v = sm.a.at[w * 64 + lane];
#pragma unroll
      for (int off = 32; off; off >>= 1) v += __shfl_down(v, off);
      if (lane == 0) gstore(&S_part[(b_a * 16 + jt) * 8 + w], v);
    }
    {
      int k2 = t & 127, h = t >> 7;
      float u0 = 0.f, u1 = 0.f;
      const float* a0 = sm.a.at + h * 64;
      const float* a1 = sm.a.at + (h + 4) * 64;
#pragma unroll 8
      for (int j = 0; j < 64; ++j) {
        float xv = sm.a.Xt[j * 129 + k2];
        u0 += xv * a0[j]; u1 += xv * a1[j];
      }
      float* pp = P_part + (long)(b_a * 16 + jt) * 8 * 128;
      gstore(&pp[h * 128 + k2], u0);
      gstore(&pp[(h + 4) * 128 + k2], u1);
    }
    grid_sync(cnt, 2 + 2 * it);
    // ================= phase B =================
    if (it < 16) {  // prefetch next frame tile (f(it+1) == it)
      const float* xsrc = x + (((long)b_a * NF_ + it) * N_ + jt * 64) * D_;
#pragma unroll
      for (int i = 0; i < 4; ++i) {
        int ch = t + i * 512;
        pf[i] = *(const float4*)(xsrc + (ch >> 5) * 128 + (ch & 31) * 4);
      }
    }
    if (bid < 16) {
      int b = bid, k = t & 127, sp = t >> 7;
      SmemB& B = sm.b;
      float pa0 = 0.f, pa1 = 0.f;
#pragma unroll
      for (int j = 0; j < 16; ++j) {
        const float* pp = P_part + (long)(b * 16 + j) * 8 * 128;
        pa0 += gload(&pp[sp * 128 + k]);
        pa1 += gload(&pp[(sp + 4) * 128 + k]);
      }
      if (t < 8) {
        float ss = 0.f;
#pragma unroll
        for (int j = 0; j < 16; ++j) ss += gload(&S_part[(b * 16 + j) * 8 + t]);
        B.ssm[t] = ss;
      }
      __syncthreads();
      B.Pk[sp * 128 + k] = pa0 / B.ssm[sp];
      B.Pk[(sp + 4) * 128 + k] = pa1 / B.ssm[sp + 4];
      __syncthreads();
      {  // upd = Wv @ Pk + bv
        float a0 = bv[k], a1 = bv[k];
        const float4* wr = (const float4*)(Wv + k * 128);
#pragma unroll 8
        for (int i = 0; i < 32; ++i) {
          float4 wv = wr[i];
          float4 x0 = *(const float4*)(B.Pk + sp * 128 + i * 4);
          float4 x1 = *(const float4*)(B.Pk + (sp + 4) * 128 + i * 4);
          a0 += wv.x * x0.x + wv.y * x0.y + wv.z * x0.z + wv.w * x0.w;
          a1 += wv.x * x1.x + wv.y * x1.y + wv.z * x1.z + wv.w * x1.w;
        }
        B.upd[sp * 128 + k] = a0; B.upd[(sp + 4) * 128 + k] = a1;
      }
      __syncthreads();
      if (t < 384) dorow8(Wih + t * 128, bih[t], B.upd, B.gi, t);
      {
        int rh = (t >= 384) ? (t - 384) : (t < 256 ? 128 + t : -1);
        if (rh >= 0) dorow8(Whh + rh * 128, bhh[rh], slot_sh, B.gh, rh);
      }
      __syncthreads();
      if (t < 128) {
#pragma unroll
        for (int s = 0; s < 8; ++s) {
          float r = sigm(B.gi[s * 384 + t] + B.gh[s * 384 + t]);
          float z = sigm(B.gi[s * 384 + 128 + t] + B.gh[s * 384 + 128 + t]);
          float n = tanh_f(B.gi[s * 384 + 256 + t] + r * B.gh[s * 384 + 256 + t]);
          B.hn[s * 128 + t] = (1.f - z) * n + z * slot_sh[s * 128 + t];
        }
      }
      stats8(B.hn, B.mst, B.ist, 1e-5f);
      if (t < 128) {
        float g = g_ff[t], be = be_ff[t];
#pragma unroll
        for (int s = 0; s < 8; ++s)
          B.buf[s * 128 + t] = (B.hn[s * 128 + t] - B.mst[s]) * B.ist[s] * g + be;
      }
      __syncthreads();
      {  // hid = relu(W1 @ buf + b1)
        float a0 = b1[k], a1 = b1[k];
        const float4* wr = (const float4*)(W1 + k * 128);
#pragma unroll 8
        for (int i = 0; i < 32; ++i) {
          float4 wv = wr[i];
          float4 x0 = *(const float4*)(B.buf + sp * 128 + i * 4);
          float4 x1 = *(const float4*)(B.buf + (sp + 4) * 128 + i * 4);
          a0 += wv.x * x0.x + wv.y * x0.y + wv.z * x0.z + wv.w * x0.w;
          a1 += wv.x * x1.x + wv.y * x1.y + wv.z * x1.z + wv.w * x1.w;
        }
        B.hid[sp * 128 + k] = fmaxf(a0, 0.f);
        B.hid[(sp + 4) * 128 + k] = fmaxf(a1, 0.f);
      }
      __syncthreads();
      {  // sn = hn + W2 @ hid + b2 -> slot_sh, out_slots
        float a0 = b2[k], a1 = b2[k];
        const float4* wr = (const float4*)(W2 + k * 128);
#pragma unroll 8
        for (int i = 0; i < 32; ++i) {
          float4 wv = wr[i];
          float4 x0 = *(const float4*)(B.hid + sp * 128 + i * 4);
          float4 x1 = *(const float4*)(B.hid + (sp + 4) * 128 + i * 4);
          a0 += wv.x * x0.x + wv.y * x0.y + wv.z * x0.z + wv.w * x0.w;
          a1 += wv.x * x1.x + wv.y * x1.y + wv.z * x1.z + wv.w * x1.w;
        }
        float sn0 = B.hn[sp * 128 + k] + a0;
        float sn1 = B.hn[(sp + 4) * 128 + k] + a1;
        slot_sh[sp * 128 + k] = sn0;
        slot_sh[(sp + 4) * 128 + k] = sn1;
        if (wo) {
          out_slots[(((long)b * NF_ + f) * S_ + sp) * D_ + k] = sn0;
          out_slots[(((long)b * NF_ + f) * S_ + sp + 4) * D_ + k] = sn1;
        }
      }
      if (it < 16)
        slots_to_q(B, slot_sh, g_sl, be_sl, Wq, bq, Wk, bk, qW_g, qb_g, b);
    }
    if (it < 16) grid_sync(cnt, 3 + 2 * it);
  }
}

extern "C" void kernel_launch(void* const* d_in, const int* in_sizes, int n_in,
                              void* d_out, int out_size, void* d_ws, size_t ws_size,
                              hipStream_t stream) {
  const float* inputs     = (const float*)d_in[0];
  const float* slots_init = (const float*)d_in[1];
  const float* Wq  = (const float*)d_in[2];
  const float* bq  = (const float*)d_in[3];
  const float* Wk  = (const float*)d_in[4];
  const float* bk  = (const float*)d_in[5];
  const float* Wv  = (const float*)d_in[6];
  const float* bv  = (const float*)d_in[7];
  const float* W1  = (const float*)d_in[8];
  const float* b1  = (const float*)d_in[9];
  const float* W2  = (const float*)d_in[10];
  const float* b2  = (const float*)d_in[11];
  const float* Wih = (const float*)d_in[12];
  const float* Whh = (const float*)d_in[13];
  const float* bih = (const float*)d_in[14];
  const float* bhh = (const float*)d_in[15];
  const float* g_in  = (const float*)d_in[16];
  const float* be_in = (const float*)d_in[17];
  const float* g_sl  = (const float*)d_in[18];
  const float* be_sl = (const float*)d_in[19];
  const float* g_ff  = (const float*)d_in[20];
  const float* be_ff = (const float*)d_in[21];

  float* out_slots = (float*)d_out;
  float* out_attn  = out_slots + (size_t)B_ * NF_ * S_ * D_;

  char* ws = (char*)d_ws;
  unsigned* cnt  = (unsigned*)ws;                    // 64 B (zeroed below)
  float* qW_g    = (float*)(ws + 1024);              // 64 KB
  float* qb_g    = (float*)(ws + 1024 + 65536);      // 512 B
  float* P_part  = (float*)(ws + 67072);             // 1 MB
  float* S_part  = (float*)(ws + 67072 + 1048576);   // 8 KB

  hipMemsetAsync(d_ws, 0, 256, stream);  // reset barrier counter (graph-capturable)

  slot_persist<<<NB, NT, 0, stream>>>(inputs, slots_init, Wq, bq, Wk, bk, Wv, bv,
      W1, b1, W2, b2, Wih, Whh, bih, bhh, g_in, be_in, g_sl, be_sl, g_ff, be_ff,
      out_slots, out_attn, cnt, qW_g, qb_g, P_part, S_part);
}

// Round 6
// 969.909 us; speedup vs baseline: 2.0297x; 1.4527x over previous
//
#include <hip/hip_runtime.h>

#define B_ 16
#define NF_ 16
#define N_ 1024
#define D_ 128
#define S_ 8
#define SCALE_ 0.08838834764831845f
#define NB 256
#define NT 512

struct SmemA {
  float Xt[64 * 129];       // normalized in place
  float qWs[1024];
  float at[512];
  float rowsum[64], rowsum2[64];
  float qbs[8];
};
struct SmemB {  // per-(b,s) phase-B scratch (~2 KB)
  float Pk[128], upd[128], hn[128], buf[128], hid[128], qsh[128], nrm[128];
  float gi[384], gh[384];
  float red[4], ssm;
};
union Smem { SmemA a; SmemB b; };

// ---- fence-free device-coherent accessors (sc1 ops, no L2 writeback/invalidate) ----
__device__ __forceinline__ float gload(const float* p) {
  return __hip_atomic_load(p, __ATOMIC_RELAXED, __HIP_MEMORY_SCOPE_AGENT);
}
__device__ __forceinline__ void gstore(float* p, float v) {
  __hip_atomic_store(p, v, __ATOMIC_RELAXED, __HIP_MEMORY_SCOPE_AGENT);
}

__device__ __forceinline__ void grid_sync(unsigned* cnt, unsigned epoch) {
  __syncthreads();  // compiler drains vmcnt before s_barrier -> our sc1 stores are visible
  if (threadIdx.x == 0) {
    __builtin_amdgcn_s_waitcnt(0);
    __atomic_signal_fence(__ATOMIC_ACQ_REL);
    __hip_atomic_fetch_add(cnt, 1u, __ATOMIC_RELAXED, __HIP_MEMORY_SCOPE_AGENT);
    unsigned target = NB * epoch;
    while (__hip_atomic_load(cnt, __ATOMIC_RELAXED, __HIP_MEMORY_SCOPE_AGENT) < target)
      __builtin_amdgcn_s_sleep(4);
    __atomic_signal_fence(__ATOMIC_ACQ_REL);
  }
  __syncthreads();
}

// acc += dot(fp32 row of 128, fp32 x[128] in LDS); acc starts at bias
__device__ __forceinline__ float dot128f(const float* __restrict__ wrow, const float* x, float acc) {
  const float4* w = (const float4*)wrow;
#pragma unroll
  for (int i = 0; i < 32; ++i) {
    float4 v = w[i];
    const float4 xv = *(const float4*)(x + i * 4);
    acc += v.x * xv.x + v.y * xv.y + v.z * xv.z + v.w * xv.w;
  }
  return acc;
}

// Block-wide mean / rsqrt(var+eps) over 128 values held by threads t<128. ALL threads call.
__device__ __forceinline__ void stats128(float v, int t, float* red, float& m, float& inv, float eps) {
  __syncthreads();
  float s = (t < 128) ? v : 0.f;
  float s2 = (t < 128) ? v * v : 0.f;
#pragma unroll
  for (int off = 32; off; off >>= 1) { s += __shfl_down(s, off); s2 += __shfl_down(s2, off); }
  if (t == 0)  { red[0] = s; red[2] = s2; }
  if (t == 64) { red[1] = s; red[3] = s2; }
  __syncthreads();
  m = (red[0] + red[1]) * (1.f / 128.f);
  float var = (red[2] + red[3]) * (1.f / 128.f) - m * m;
  inv = rsqrtf(var + eps);
}

__device__ __forceinline__ float sigm(float x) { return 1.f / (1.f + __expf(-x)); }
__device__ __forceinline__ float tanh_f(float x) { return 1.f - 2.f / (1.f + __expf(2.f * x)); }

// slot (LDS,128) -> LN_sl -> q -> qW col + qb (sc1 global). All 512 threads of block call.
__device__ void q_project(SmemB& B, const float* slot,
    const float* __restrict__ g_sl, const float* __restrict__ be_sl,
    const float* __restrict__ Wq, const float* __restrict__ bq,
    const float* __restrict__ Wk, const float* __restrict__ bk,
    float* qW_g, float* qb_g, int bs) {
  int t = threadIdx.x;
  float m, inv;
  float sv = (t < 128) ? slot[t] : 0.f;
  stats128(sv, t, B.red, m, inv, 1e-5f);
  if (t < 128) B.nrm[t] = (sv - m) * inv * g_sl[t] + be_sl[t];
  __syncthreads();
  if (t < 128) B.qsh[t] = dot128f(Wq + t * 128, B.nrm, bq[t]);
  __syncthreads();
  if (t < 128) {
    float a = 0.f;
#pragma unroll 16
    for (int d = 0; d < 128; ++d) a += B.qsh[d] * Wk[d * 128 + t];
    gstore(&qW_g[bs * 128 + t], a);
    float p = B.qsh[t] * bk[t];
#pragma unroll
    for (int off = 32; off; off >>= 1) p += __shfl_down(p, off);
    if (t == 0)  B.red[0] = p;
    if (t == 64) B.red[1] = p;
  }
  __syncthreads();
  if (t == 0) gstore(&qb_g[bs], B.red[0] + B.red[1]);
}

__global__ __launch_bounds__(NT) void slot_persist(
    const float* __restrict__ x, const float* __restrict__ slots_init,
    const float* __restrict__ Wq, const float* __restrict__ bq,
    const float* __restrict__ Wk, const float* __restrict__ bk,
    const float* __restrict__ Wv, const float* __restrict__ bv,
    const float* __restrict__ W1, const float* __restrict__ b1,
    const float* __restrict__ W2, const float* __restrict__ b2,
    const float* __restrict__ Wih, const float* __restrict__ Whh,
    const float* __restrict__ bih, const float* __restrict__ bhh,
    const float* __restrict__ g_in, const float* __restrict__ be_in,
    const float* __restrict__ g_sl, const float* __restrict__ be_sl,
    const float* __restrict__ g_ff, const float* __restrict__ be_ff,
    float* out_slots, float* out_attn,
    unsigned* cnt, float* qW_g, float* qb_g, float* P_part, float* S_part) {
  __shared__ __align__(16) Smem sm;
  __shared__ __align__(16) float slot_sh[128];   // this block's (b,s) slot state
  __shared__ float gs[128], bs_[128];
  int t = threadIdx.x, bid = blockIdx.x;
  int b_a = bid >> 4, jt = bid & 15;             // phase-A role
  int b_u = bid >> 3, s_u = bid & 7;             // phase-B role (bid < 128)

  if (t < 128) { gs[t] = g_in[t]; bs_[t] = be_in[t]; }
  if (bid < 128) {
    if (t < 128) slot_sh[t] = slots_init[s_u * 128 + t];
    q_project(sm.b, slot_sh, g_sl, be_sl, Wq, bq, Wk, bk, qW_g, qb_g, bid);
  }
  float4 pf[4];
  {
    const float* xsrc = x + (((long)b_a * NF_ + 0) * N_ + jt * 64) * D_;
#pragma unroll
    for (int i = 0; i < 4; ++i) {
      int ch = t + i * 512;
      pf[i] = *(const float4*)(xsrc + (ch >> 5) * 128 + (ch & 31) * 4);
    }
  }
  grid_sync(cnt, 1);

  for (int it = 0; it < 17; ++it) {
    int f = (it == 0) ? 0 : it - 1;
    int wo = it > 0;
    // ================= phase A (all 256 blocks) =================
#pragma unroll
    for (int i = 0; i < 4; ++i) {
      int ch = t + i * 512;
      float* dst = sm.a.Xt + (ch >> 5) * 129 + (ch & 31) * 4;
      dst[0] = pf[i].x; dst[1] = pf[i].y; dst[2] = pf[i].z; dst[3] = pf[i].w;
    }
    sm.a.qWs[t] = gload(&qW_g[b_a * 1024 + t]);
    sm.a.qWs[512 + t] = gload(&qW_g[b_a * 1024 + 512 + t]);
    if (t < 8) sm.a.qbs[t] = gload(&qb_g[b_a * 8 + t]);
    __syncthreads();
    int r8 = t >> 3, p8 = t & 7;
    {
      const float* row = sm.a.Xt + r8 * 129 + p8 * 16;
      float s1 = 0.f, s2 = 0.f;
#pragma unroll
      for (int i = 0; i < 16; ++i) { float v = row[i]; s1 += v; s2 += v * v; }
      s1 += __shfl_down(s1, 1); s2 += __shfl_down(s2, 1);
      s1 += __shfl_down(s1, 2); s2 += __shfl_down(s2, 2);
      s1 += __shfl_down(s1, 4); s2 += __shfl_down(s2, 4);
      if (p8 == 0) { sm.a.rowsum[r8] = s1; sm.a.rowsum2[r8] = s2; }
    }
    __syncthreads();
    {
      float m = sm.a.rowsum[r8] * (1.f / 128.f);
      float var = sm.a.rowsum2[r8] * (1.f / 128.f) - m * m;
      float inv = rsqrtf(var + 1e-5f);
      float* row = sm.a.Xt + r8 * 129 + p8 * 16;
      const float* gg = gs + p8 * 16;
      const float* bb = bs_ + p8 * 16;
#pragma unroll
      for (int i = 0; i < 16; ++i) row[i] = (row[i] - m) * inv * gg[i] + bb[i];
    }
    __syncthreads();
    {
      int s = t >> 6, j = t & 63;
      const float* qq = sm.a.qWs + s * 128;
      const float* xr = sm.a.Xt + j * 129;
      float d = 0.f;
#pragma unroll
      for (int k = 0; k < 128; ++k) d += xr[k] * qq[k];
      sm.a.at[s * 64 + j] = (d + sm.a.qbs[s]) * SCALE_;
    }
    __syncthreads();
    if (t < 64) {
      float vals[8], mx = -1e30f;
#pragma unroll
      for (int s = 0; s < 8; ++s) { vals[s] = sm.a.at[s * 64 + t]; mx = fmaxf(mx, vals[s]); }
      float sum = 0.f;
#pragma unroll
      for (int s = 0; s < 8; ++s) { vals[s] = __expf(vals[s] - mx); sum += vals[s]; }
      float rr = 1.f / sum;
#pragma unroll
      for (int s = 0; s < 8; ++s) { vals[s] = vals[s] * rr + 1e-8f; sm.a.at[s * 64 + t] = vals[s]; }
      if (wo) {
#pragma unroll
        for (int s = 0; s < 8; ++s)
          out_attn[(((long)b_a * NF_ + f) * S_ + s) * N_ + jt * 64 + t] = vals[s];
      }
    }
    __syncthreads();
    {
      int w = t >> 6, lane = t & 63;
      float v = sm.a.at[w * 64 + lane];
#pragma unroll
      for (int off = 32; off; off >>= 1) v += __shfl_down(v, off);
      if (lane == 0) gstore(&S_part[(b_a * 16 + jt) * 8 + w], v);
    }
    {
      int k2 = t & 127, h = t >> 7;
      float u0 = 0.f, u1 = 0.f;
      const float* a0 = sm.a.at + h * 64;
      const float* a1 = sm.a.at + (h + 4) * 64;
#pragma unroll 8
      for (int j = 0; j < 64; ++j) {
        float xv = sm.a.Xt[j * 129 + k2];
        u0 += xv * a0[j]; u1 += xv * a1[j];
      }
      float* pp = P_part + (long)(b_a * 16 + jt) * 8 * 128;
      gstore(&pp[h * 128 + k2], u0);
      gstore(&pp[(h + 4) * 128 + k2], u1);
    }
    grid_sync(cnt, 2 + 2 * it);
    // ================= phase B (blocks 0..127: one per (b,s)) =================
    if (it < 16) {  // prefetch next frame tile (f(it+1) == it)
      const float* xsrc = x + (((long)b_a * NF_ + it) * N_ + jt * 64) * D_;
#pragma unroll
      for (int i = 0; i < 4; ++i) {
        int ch = t + i * 512;
        pf[i] = *(const float4*)(xsrc + (ch >> 5) * 128 + (ch & 31) * 4);
      }
    }
    if (bid < 128) {
      SmemB& B = sm.b;
      int b = b_u, s = s_u;
      // stage 1: reduce P (t<128) and S (t<16)
      if (t < 128) {
        float pa = 0.f;
#pragma unroll
        for (int j = 0; j < 16; ++j)
          pa += gload(&P_part[(long)((b * 16 + j) * 8 + s) * 128 + t]);
        B.Pk[t] = pa;
      }
      if (t < 16) {
        float sv = gload(&S_part[(b * 16 + t) * 8 + s]);
        sv += __shfl_down(sv, 8); sv += __shfl_down(sv, 4);
        sv += __shfl_down(sv, 2); sv += __shfl_down(sv, 1);
        if (t == 0) B.ssm = sv;
      }
      __syncthreads();
      // stage 2: upd = Wv@Pk/ss + bv (t<128); gh = Whh@hprev (t>=128 -> rows 0..383)
      if (t < 128) {
        float a = dot128f(Wv + t * 128, B.Pk, 0.f);
        B.upd[t] = a / B.ssm + bv[t];
      } else {
        int r = t - 128;
        B.gh[r] = dot128f(Whh + r * 128, slot_sh, bhh[r]);
      }
      __syncthreads();
      // stage 3: gi = Wih@upd (t<384)
      if (t < 384) B.gi[t] = dot128f(Wih + t * 128, B.upd, bih[t]);
      __syncthreads();
      // stage 4: gates -> hn
      if (t < 128) {
        float r = sigm(B.gi[t] + B.gh[t]);
        float z = sigm(B.gi[128 + t] + B.gh[128 + t]);
        float n = tanh_f(B.gi[256 + t] + r * B.gh[256 + t]);
        B.hn[t] = (1.f - z) * n + z * slot_sh[t];
      }
      // stage 5: LN_ff(hn) -> buf
      float m, inv;
      float hv = (t < 128) ? B.hn[t] : 0.f;  // hn written by stage4; stats128 syncs first
      stats128(hv, t, B.red, m, inv, 1e-5f);
      if (t < 128) B.buf[t] = (hv - m) * inv * g_ff[t] + be_ff[t];
      __syncthreads();
      // stage 6: hid = relu(W1@buf + b1)
      if (t < 128) B.hid[t] = fmaxf(dot128f(W1 + t * 128, B.buf, b1[t]), 0.f);
      __syncthreads();
      // stage 7: sn = hn + W2@hid + b2 -> slot_sh, out
      if (t < 128) {
        float ffv = dot128f(W2 + t * 128, B.hid, b2[t]);
        float sn = B.hn[t] + ffv;
        slot_sh[t] = sn;
        if (wo) out_slots[(((long)b * NF_ + f) * S_ + s) * D_ + t] = sn;
      }
      __syncthreads();
      // stages 8-10: next-frame q projection
      if (it < 16)
        q_project(B, slot_sh, g_sl, be_sl, Wq, bq, Wk, bk, qW_g, qb_g, bid);
    }
    if (it < 16) grid_sync(cnt, 3 + 2 * it);
  }
}

extern "C" void kernel_launch(void* const* d_in, const int* in_sizes, int n_in,
                              void* d_out, int out_size, void* d_ws, size_t ws_size,
                              hipStream_t stream) {
  const float* inputs     = (const float*)d_in[0];
  const float* slots_init = (const float*)d_in[1];
  const float* Wq  = (const float*)d_in[2];
  const float* bq  = (const float*)d_in[3];
  const float* Wk  = (const float*)d_in[4];
  const float* bk  = (const float*)d_in[5];
  const float* Wv  = (const float*)d_in[6];
  const float* bv  = (const float*)d_in[7];
  const float* W1  = (const float*)d_in[8];
  const float* b1  = (const float*)d_in[9];
  const float* W2  = (const float*)d_in[10];
  const float* b2  = (const float*)d_in[11];
  const float* Wih = (const float*)d_in[12];
  const float* Whh = (const float*)d_in[13];
  const float* bih = (const float*)d_in[14];
  const float* bhh = (const float*)d_in[15];
  const float* g_in  = (const float*)d_in[16];
  const float* be_in = (const float*)d_in[17];
  const float* g_sl  = (const float*)d_in[18];
  const float* be_sl = (const float*)d_in[19];
  const float* g_ff  = (const float*)d_in[20];
  const float* be_ff = (const float*)d_in[21];

  float* out_slots = (float*)d_out;
  float* out_attn  = out_slots + (size_t)B_ * NF_ * S_ * D_;

  char* ws = (char*)d_ws;
  unsigned* cnt  = (unsigned*)ws;                    // 64 B (zeroed below)
  float* qW_g    = (float*)(ws + 1024);              // 64 KB
  float* qb_g    = (float*)(ws + 1024 + 65536);      // 512 B
  float* P_part  = (float*)(ws + 67072);             // 1 MB
  float* S_part  = (float*)(ws + 67072 + 1048576);   // 8 KB

  hipMemsetAsync(d_ws, 0, 256, stream);  // reset barrier counter (graph-capturable)

  slot_persist<<<NB, NT, 0, stream>>>(inputs, slots_init, Wq, bq, Wk, bk, Wv, bv,
      W1, b1, W2, b2, Wih, Whh, bih, bhh, g_in, be_in, g_sl, be_sl, g_ff, be_ff,
      out_slots, out_attn, cnt, qW_g, qb_g, P_part, S_part);
}

// Round 7
// 857.662 us; speedup vs baseline: 2.2954x; 1.1309x over previous
//
#include <hip/hip_runtime.h>

#define B_ 16
#define NF_ 16
#define N_ 1024
#define D_ 128
#define S_ 8
#define SCALE_ 0.08838834764831845f
#define NB 256
#define NT 512

struct SmemA {
  float Xt[64 * 129];       // normalized in place
  float qWs[1024];
  float at[512];
  float rowsum[64], rowsum2[64];
  float qbs[8];
};
struct SmemB {  // per-(b,s) phase-B scratch (~2 KB)
  float Pk[128], upd[128], hn[128], buf[128], hid[128], qsh[128], nrm[128];
  float gi[384], gh[384];
  float red[4], ssm;
};
union Smem { SmemA a; SmemB b; };

// ---- fence-free device-coherent accessors (sc1 ops, no L2 writeback/invalidate) ----
__device__ __forceinline__ float gload(const float* p) {
  return __hip_atomic_load(p, __ATOMIC_RELAXED, __HIP_MEMORY_SCOPE_AGENT);
}
__device__ __forceinline__ void gstore(float* p, float v) {
  __hip_atomic_store(p, v, __ATOMIC_RELAXED, __HIP_MEMORY_SCOPE_AGENT);
}

// Split-line barrier: arrivals hit `cnt`; spinners poll only `flag` (different page).
// The arrival that completes epoch e stores e to flag. cnt/flag monotonic per launch.
__device__ __forceinline__ void grid_sync(unsigned* cnt, unsigned* flag, unsigned epoch) {
  __syncthreads();  // drains vmcnt -> all our sc1 stores are at the coherence point
  if (threadIdx.x == 0) {
    __builtin_amdgcn_s_waitcnt(0);
    unsigned old = __hip_atomic_fetch_add(cnt, 1u, __ATOMIC_RELAXED, __HIP_MEMORY_SCOPE_AGENT);
    if (old == NB * epoch - 1u) {
      __hip_atomic_store(flag, epoch, __ATOMIC_RELAXED, __HIP_MEMORY_SCOPE_AGENT);
    } else {
      while (__hip_atomic_load(flag, __ATOMIC_RELAXED, __HIP_MEMORY_SCOPE_AGENT) < epoch)
        __builtin_amdgcn_s_sleep(2);
    }
  }
  __syncthreads();
}

// acc += dot(fp32 row of 128, fp32 x[128] in LDS); acc starts at bias
__device__ __forceinline__ float dot128f(const float* __restrict__ wrow, const float* x, float acc) {
  const float4* w = (const float4*)wrow;
#pragma unroll
  for (int i = 0; i < 32; ++i) {
    float4 v = w[i];
    const float4 xv = *(const float4*)(x + i * 4);
    acc += v.x * xv.x + v.y * xv.y + v.z * xv.z + v.w * xv.w;
  }
  return acc;
}

// Block-wide mean / rsqrt(var+eps) over 128 values held by threads t<128. ALL threads call.
__device__ __forceinline__ void stats128(float v, int t, float* red, float& m, float& inv, float eps) {
  __syncthreads();
  float s = (t < 128) ? v : 0.f;
  float s2 = (t < 128) ? v * v : 0.f;
#pragma unroll
  for (int off = 32; off; off >>= 1) { s += __shfl_down(s, off); s2 += __shfl_down(s2, off); }
  if (t == 0)  { red[0] = s; red[2] = s2; }
  if (t == 64) { red[1] = s; red[3] = s2; }
  __syncthreads();
  m = (red[0] + red[1]) * (1.f / 128.f);
  float var = (red[2] + red[3]) * (1.f / 128.f) - m * m;
  inv = rsqrtf(var + eps);
}

__device__ __forceinline__ float sigm(float x) { return 1.f / (1.f + __expf(-x)); }
__device__ __forceinline__ float tanh_f(float x) { return 1.f - 2.f / (1.f + __expf(2.f * x)); }

// slot (LDS,128) -> LN_sl -> q -> qW col + qb (sc1 global). All 512 threads of block call.
__device__ void q_project(SmemB& B, const float* slot,
    const float* __restrict__ g_sl, const float* __restrict__ be_sl,
    const float* __restrict__ Wq, const float* __restrict__ bq,
    const float* __restrict__ Wk, const float* __restrict__ bk,
    float* qW_g, float* qb_g, int bs) {
  int t = threadIdx.x;
  float m, inv;
  float sv = (t < 128) ? slot[t] : 0.f;
  stats128(sv, t, B.red, m, inv, 1e-5f);
  if (t < 128) B.nrm[t] = (sv - m) * inv * g_sl[t] + be_sl[t];
  __syncthreads();
  if (t < 128) B.qsh[t] = dot128f(Wq + t * 128, B.nrm, bq[t]);
  __syncthreads();
  if (t < 128) {
    float a = 0.f;
#pragma unroll 16
    for (int d = 0; d < 128; ++d) a += B.qsh[d] * Wk[d * 128 + t];
    gstore(&qW_g[bs * 128 + t], a);
    float p = B.qsh[t] * bk[t];
#pragma unroll
    for (int off = 32; off; off >>= 1) p += __shfl_down(p, off);
    if (t == 0)  B.red[0] = p;
    if (t == 64) B.red[1] = p;
  }
  __syncthreads();
  if (t == 0) gstore(&qb_g[bs], B.red[0] + B.red[1]);
}

__global__ __launch_bounds__(NT) void slot_persist(
    const float* __restrict__ x, const float* __restrict__ slots_init,
    const float* __restrict__ Wq, const float* __restrict__ bq,
    const float* __restrict__ Wk, const float* __restrict__ bk,
    const float* __restrict__ Wv, const float* __restrict__ bv,
    const float* __restrict__ W1, const float* __restrict__ b1,
    const float* __restrict__ W2, const float* __restrict__ b2,
    const float* __restrict__ Wih, const float* __restrict__ Whh,
    const float* __restrict__ bih, const float* __restrict__ bhh,
    const float* __restrict__ g_in, const float* __restrict__ be_in,
    const float* __restrict__ g_sl, const float* __restrict__ be_sl,
    const float* __restrict__ g_ff, const float* __restrict__ be_ff,
    float* out_slots, float* out_attn,
    unsigned* cnt, unsigned* flag,
    float* qW_g, float* qb_g, float* P_part, float* S_part) {
  __shared__ __align__(16) Smem sm;
  __shared__ __align__(16) float slot_sh[128];   // this block's (b,s) slot state
  __shared__ float gs[128], bs_[128];
  int t = threadIdx.x, bid = blockIdx.x;
  int b_a = bid >> 4, jt = bid & 15;             // phase-A role
  int b_u = bid >> 3, s_u = bid & 7;             // phase-B role (bid < 128)

  if (t < 128) { gs[t] = g_in[t]; bs_[t] = be_in[t]; }
  if (bid < 128) {
    if (t < 128) slot_sh[t] = slots_init[s_u * 128 + t];
    q_project(sm.b, slot_sh, g_sl, be_sl, Wq, bq, Wk, bk, qW_g, qb_g, bid);
  }
  float4 pf[4];
  {
    const float* xsrc = x + (((long)b_a * NF_ + 0) * N_ + jt * 64) * D_;
#pragma unroll
    for (int i = 0; i < 4; ++i) {
      int ch = t + i * 512;
      pf[i] = *(const float4*)(xsrc + (ch >> 5) * 128 + (ch & 31) * 4);
    }
  }
  grid_sync(cnt, flag, 1);

  for (int it = 0; it < 17; ++it) {
    int f = (it == 0) ? 0 : it - 1;
    int wo = it > 0;
    // ================= phase A (all 256 blocks) =================
#pragma unroll
    for (int i = 0; i < 4; ++i) {
      int ch = t + i * 512;
      float* dst = sm.a.Xt + (ch >> 5) * 129 + (ch & 31) * 4;
      dst[0] = pf[i].x; dst[1] = pf[i].y; dst[2] = pf[i].z; dst[3] = pf[i].w;
    }
    sm.a.qWs[t] = gload(&qW_g[b_a * 1024 + t]);
    sm.a.qWs[512 + t] = gload(&qW_g[b_a * 1024 + 512 + t]);
    if (t < 8) sm.a.qbs[t] = gload(&qb_g[b_a * 8 + t]);
    __syncthreads();
    int r8 = t >> 3, p8 = t & 7;
    {
      const float* row = sm.a.Xt + r8 * 129 + p8 * 16;
      float s1 = 0.f, s2 = 0.f;
#pragma unroll
      for (int i = 0; i < 16; ++i) { float v = row[i]; s1 += v; s2 += v * v; }
      s1 += __shfl_down(s1, 1); s2 += __shfl_down(s2, 1);
      s1 += __shfl_down(s1, 2); s2 += __shfl_down(s2, 2);
      s1 += __shfl_down(s1, 4); s2 += __shfl_down(s2, 4);
      if (p8 == 0) { sm.a.rowsum[r8] = s1; sm.a.rowsum2[r8] = s2; }
    }
    __syncthreads();
    {
      float m = sm.a.rowsum[r8] * (1.f / 128.f);
      float var = sm.a.rowsum2[r8] * (1.f / 128.f) - m * m;
      float inv = rsqrtf(var + 1e-5f);
      float* row = sm.a.Xt + r8 * 129 + p8 * 16;
      const float* gg = gs + p8 * 16;
      const float* bb = bs_ + p8 * 16;
#pragma unroll
      for (int i = 0; i < 16; ++i) row[i] = (row[i] - m) * inv * gg[i] + bb[i];
    }
    __syncthreads();
    {
      int s = t >> 6, j = t & 63;
      const float* qq = sm.a.qWs + s * 128;
      const float* xr = sm.a.Xt + j * 129;
      float d = 0.f;
#pragma unroll
      for (int k = 0; k < 128; ++k) d += xr[k] * qq[k];
      sm.a.at[s * 64 + j] = (d + sm.a.qbs[s]) * SCALE_;
    }
    __syncthreads();
    if (t < 64) {
      float vals[8], mx = -1e30f;
#pragma unroll
      for (int s = 0; s < 8; ++s) { vals[s] = sm.a.at[s * 64 + t]; mx = fmaxf(mx, vals[s]); }
      float sum = 0.f;
#pragma unroll
      for (int s = 0; s < 8; ++s) { vals[s] = __expf(vals[s] - mx); sum += vals[s]; }
      float rr = 1.f / sum;
#pragma unroll
      for (int s = 0; s < 8; ++s) { vals[s] = vals[s] * rr + 1e-8f; sm.a.at[s * 64 + t] = vals[s]; }
      if (wo) {
#pragma unroll
        for (int s = 0; s < 8; ++s)
          out_attn[(((long)b_a * NF_ + f) * S_ + s) * N_ + jt * 64 + t] = vals[s];
      }
    }
    __syncthreads();
    {
      int w = t >> 6, lane = t & 63;
      float v = sm.a.at[w * 64 + lane];
#pragma unroll
      for (int off = 32; off; off >>= 1) v += __shfl_down(v, off);
      if (lane == 0) gstore(&S_part[(b_a * 16 + jt) * 8 + w], v);
    }
    {
      int k2 = t & 127, h = t >> 7;
      float u0 = 0.f, u1 = 0.f;
      const float* a0 = sm.a.at + h * 64;
      const float* a1 = sm.a.at + (h + 4) * 64;
#pragma unroll 8
      for (int j = 0; j < 64; ++j) {
        float xv = sm.a.Xt[j * 129 + k2];
        u0 += xv * a0[j]; u1 += xv * a1[j];
      }
      float* pp = P_part + (long)(b_a * 16 + jt) * 8 * 128;
      gstore(&pp[h * 128 + k2], u0);
      gstore(&pp[(h + 4) * 128 + k2], u1);
    }
    grid_sync(cnt, flag, 2 + 2 * it);
    // ================= phase B (blocks 0..127: one per (b,s)) =================
    if (it < 16) {  // prefetch next frame tile (f(it+1) == it)
      const float* xsrc = x + (((long)b_a * NF_ + it) * N_ + jt * 64) * D_;
#pragma unroll
      for (int i = 0; i < 4; ++i) {
        int ch = t + i * 512;
        pf[i] = *(const float4*)(xsrc + (ch >> 5) * 128 + (ch & 31) * 4);
      }
    }
    if (bid < 128) {
      SmemB& B = sm.b;
      int b = b_u, s = s_u;
      // stage 1: reduce P (t<128) and S (t<16)
      if (t < 128) {
        float pa = 0.f;
#pragma unroll
        for (int j = 0; j < 16; ++j)
          pa += gload(&P_part[(long)((b * 16 + j) * 8 + s) * 128 + t]);
        B.Pk[t] = pa;
      }
      if (t < 16) {
        float sv = gload(&S_part[(b * 16 + t) * 8 + s]);
        sv += __shfl_down(sv, 8); sv += __shfl_down(sv, 4);
        sv += __shfl_down(sv, 2); sv += __shfl_down(sv, 1);
        if (t == 0) B.ssm = sv;
      }
      __syncthreads();
      // stage 2: upd = Wv@Pk/ss + bv (t<128); gh = Whh@hprev (t>=128 -> rows 0..383)
      if (t < 128) {
        float a = dot128f(Wv + t * 128, B.Pk, 0.f);
        B.upd[t] = a / B.ssm + bv[t];
      } else {
        int r = t - 128;
        B.gh[r] = dot128f(Whh + r * 128, slot_sh, bhh[r]);
      }
      __syncthreads();
      // stage 3: gi = Wih@upd (t<384)
      if (t < 384) B.gi[t] = dot128f(Wih + t * 128, B.upd, bih[t]);
      __syncthreads();
      // stage 4: gates -> hn
      if (t < 128) {
        float r = sigm(B.gi[t] + B.gh[t]);
        float z = sigm(B.gi[128 + t] + B.gh[128 + t]);
        float n = tanh_f(B.gi[256 + t] + r * B.gh[256 + t]);
        B.hn[t] = (1.f - z) * n + z * slot_sh[t];
      }
      // stage 5: LN_ff(hn) -> buf
      float m, inv;
      float hv = (t < 128) ? B.hn[t] : 0.f;  // stats128 syncs before reading
      stats128(hv, t, B.red, m, inv, 1e-5f);
      if (t < 128) B.buf[t] = (hv - m) * inv * g_ff[t] + be_ff[t];
      __syncthreads();
      // stage 6: hid = relu(W1@buf + b1)
      if (t < 128) B.hid[t] = fmaxf(dot128f(W1 + t * 128, B.buf, b1[t]), 0.f);
      __syncthreads();
      // stage 7: sn = hn + W2@hid + b2 -> slot_sh, out
      if (t < 128) {
        float ffv = dot128f(W2 + t * 128, B.hid, b2[t]);
        float sn = B.hn[t] + ffv;
        slot_sh[t] = sn;
        if (wo) out_slots[(((long)b * NF_ + f) * S_ + s) * D_ + t] = sn;
      }
      __syncthreads();
      // stages 8-10: next-frame q projection
      if (it < 16)
        q_project(B, slot_sh, g_sl, be_sl, Wq, bq, Wk, bk, qW_g, qb_g, bid);
    }
    if (it < 16) grid_sync(cnt, flag, 3 + 2 * it);
  }
}

extern "C" void kernel_launch(void* const* d_in, const int* in_sizes, int n_in,
                              void* d_out, int out_size, void* d_ws, size_t ws_size,
                              hipStream_t stream) {
  const float* inputs     = (const float*)d_in[0];
  const float* slots_init = (const float*)d_in[1];
  const float* Wq  = (const float*)d_in[2];
  const float* bq  = (const float*)d_in[3];
  const float* Wk  = (const float*)d_in[4];
  const float* bk  = (const float*)d_in[5];
  const float* Wv  = (const float*)d_in[6];
  const float* bv  = (const float*)d_in[7];
  const float* W1  = (const float*)d_in[8];
  const float* b1  = (const float*)d_in[9];
  const float* W2  = (const float*)d_in[10];
  const float* b2  = (const float*)d_in[11];
  const float* Wih = (const float*)d_in[12];
  const float* Whh = (const float*)d_in[13];
  const float* bih = (const float*)d_in[14];
  const float* bhh = (const float*)d_in[15];
  const float* g_in  = (const float*)d_in[16];
  const float* be_in = (const float*)d_in[17];
  const float* g_sl  = (const float*)d_in[18];
  const float* be_sl = (const float*)d_in[19];
  const float* g_ff  = (const float*)d_in[20];
  const float* be_ff = (const float*)d_in[21];

  float* out_slots = (float*)d_out;
  float* out_attn  = out_slots + (size_t)B_ * NF_ * S_ * D_;

  char* ws = (char*)d_ws;
  unsigned* cnt  = (unsigned*)ws;                    // page 0: arrival counter
  unsigned* flag = (unsigned*)(ws + 8192);           // page 2: release flag (separate line/slice)
  float* qW_g    = (float*)(ws + 16384);             // 64 KB
  float* qb_g    = (float*)(ws + 16384 + 65536);     // 512 B
  float* P_part  = (float*)(ws + 16384 + 66048);     // 1 MB
  float* S_part  = (float*)(ws + 16384 + 66048 + 1048576);  // 8 KB

  hipMemsetAsync(d_ws, 0, 16384, stream);  // zero cnt + flag (graph-capturable)

  slot_persist<<<NB, NT, 0, stream>>>(inputs, slots_init, Wq, bq, Wk, bk, Wv, bv,
      W1, b1, W2, b2, Wih, Whh, bih, bhh, g_in, be_in, g_sl, be_sl, g_ff, be_ff,
      out_slots, out_attn, cnt, flag, qW_g, qb_g, P_part, S_part);
}

// Round 8
// 776.270 us; speedup vs baseline: 2.5361x; 1.1049x over previous
//
#include <hip/hip_runtime.h>

#define B_ 16
#define NF_ 16
#define N_ 1024
#define D_ 128
#define S_ 8
#define SCALE_ 0.08838834764831845f
#define NB 256
#define NT 512

struct SmemA {
  float Xt[64 * 129];       // normalized in place
  float qWs[1024];
  float at[512];
  float rowsum[64], rowsum2[64];
  float qbs[8];
};
struct SmemB {  // per-(b,s) phase-B scratch (~2 KB)
  float Pk[128], upd[128], hn[128], buf[128], hid[128], qsh[128], nrm[128];
  float gi[384], gh[384];
  float red[4], ssm;
};
union Smem { SmemA a; SmemB b; };

// ---- fence-free device-coherent accessors (sc1 ops, no L2 writeback/invalidate) ----
__device__ __forceinline__ float gload(const float* p) {
  return __hip_atomic_load(p, __ATOMIC_RELAXED, __HIP_MEMORY_SCOPE_AGENT);
}
__device__ __forceinline__ void gstore(float* p, float v) {
  __hip_atomic_store(p, v, __ATOMIC_RELAXED, __HIP_MEMORY_SCOPE_AGENT);
}

// Per-batch split barrier. __syncthreads drains each wave's vmcnt (compiler emits
// s_waitcnt vmcnt(0) before s_barrier), so all the block's sc1 stores are at the
// coherence point before t0's arrival add.
__device__ __forceinline__ void arrive(unsigned* c) {
  __syncthreads();
  if (threadIdx.x == 0) {
    __builtin_amdgcn_s_waitcnt(0);
    __hip_atomic_fetch_add(c, 1u, __ATOMIC_RELAXED, __HIP_MEMORY_SCOPE_AGENT);
  }
}
__device__ __forceinline__ void wait_for(unsigned* c, unsigned target) {
  if (threadIdx.x == 0) {
    while (__hip_atomic_load(c, __ATOMIC_RELAXED, __HIP_MEMORY_SCOPE_AGENT) < target)
      __builtin_amdgcn_s_sleep(1);
  }
  __syncthreads();
}

// acc += dot(fp32 row of 128, fp32 x[128] in LDS); acc starts at bias
__device__ __forceinline__ float dot128f(const float* __restrict__ wrow, const float* x, float acc) {
  const float4* w = (const float4*)wrow;
#pragma unroll
  for (int i = 0; i < 32; ++i) {
    float4 v = w[i];
    const float4 xv = *(const float4*)(x + i * 4);
    acc += v.x * xv.x + v.y * xv.y + v.z * xv.z + v.w * xv.w;
  }
  return acc;
}

// Block-wide mean / rsqrt(var+eps) over 128 values held by threads t<128. ALL threads call.
__device__ __forceinline__ void stats128(float v, int t, float* red, float& m, float& inv, float eps) {
  __syncthreads();
  float s = (t < 128) ? v : 0.f;
  float s2 = (t < 128) ? v * v : 0.f;
#pragma unroll
  for (int off = 32; off; off >>= 1) { s += __shfl_down(s, off); s2 += __shfl_down(s2, off); }
  if (t == 0)  { red[0] = s; red[2] = s2; }
  if (t == 64) { red[1] = s; red[3] = s2; }
  __syncthreads();
  m = (red[0] + red[1]) * (1.f / 128.f);
  float var = (red[2] + red[3]) * (1.f / 128.f) - m * m;
  inv = rsqrtf(var + eps);
}

__device__ __forceinline__ float sigm(float x) { return 1.f / (1.f + __expf(-x)); }
__device__ __forceinline__ float tanh_f(float x) { return 1.f - 2.f / (1.f + __expf(2.f * x)); }

// slot (LDS,128) -> LN_sl -> q -> qW col + qb (sc1 global). All 512 threads of block call.
__device__ void q_project(SmemB& B, const float* slot,
    const float* __restrict__ g_sl, const float* __restrict__ be_sl,
    const float* __restrict__ Wq, const float* __restrict__ bq,
    const float* __restrict__ Wk, const float* __restrict__ bk,
    float* qW_g, float* qb_g, int bs) {
  int t = threadIdx.x;
  float m, inv;
  float sv = (t < 128) ? slot[t] : 0.f;
  stats128(sv, t, B.red, m, inv, 1e-5f);
  if (t < 128) B.nrm[t] = (sv - m) * inv * g_sl[t] + be_sl[t];
  __syncthreads();
  if (t < 128) B.qsh[t] = dot128f(Wq + t * 128, B.nrm, bq[t]);
  __syncthreads();
  if (t < 128) {
    float a = 0.f;
#pragma unroll 16
    for (int d = 0; d < 128; ++d) a += B.qsh[d] * Wk[d * 128 + t];
    gstore(&qW_g[bs * 128 + t], a);
    float p = B.qsh[t] * bk[t];
#pragma unroll
    for (int off = 32; off; off >>= 1) p += __shfl_down(p, off);
    if (t == 0)  B.red[0] = p;
    if (t == 64) B.red[1] = p;
  }
  __syncthreads();
  if (t == 0) gstore(&qb_g[bs], B.red[0] + B.red[1]);
}

__global__ __launch_bounds__(NT) void slot_persist(
    const float* __restrict__ x, const float* __restrict__ slots_init,
    const float* __restrict__ Wq, const float* __restrict__ bq,
    const float* __restrict__ Wk, const float* __restrict__ bk,
    const float* __restrict__ Wv, const float* __restrict__ bv,
    const float* __restrict__ W1, const float* __restrict__ b1,
    const float* __restrict__ W2, const float* __restrict__ b2,
    const float* __restrict__ Wih, const float* __restrict__ Whh,
    const float* __restrict__ bih, const float* __restrict__ bhh,
    const float* __restrict__ g_in, const float* __restrict__ be_in,
    const float* __restrict__ g_sl, const float* __restrict__ be_sl,
    const float* __restrict__ g_ff, const float* __restrict__ be_ff,
    float* out_slots, float* out_attn,
    unsigned* cntA, unsigned* cntB,
    float* qW_g, float* qb_g, float* P_part, float* S_part) {
  __shared__ __align__(16) Smem sm;
  __shared__ __align__(16) float slot_sh[128];   // this block's (b,s=jt) slot state
  __shared__ float gs[128], bs_[128];
  int t = threadIdx.x, bid = blockIdx.x;
  int b = bid >> 4, jt = bid & 15;
  bool isB = (jt < 8);                 // this block also runs phase B for slot s=jt
  unsigned* cA = cntA + (b << 6);      // 256 B apart
  unsigned* cB = cntB + (b << 6);

  if (t < 128) { gs[t] = g_in[t]; bs_[t] = be_in[t]; }
  if (isB) {
    if (t < 128) slot_sh[t] = slots_init[jt * 128 + t];
    q_project(sm.b, slot_sh, g_sl, be_sl, Wq, bq, Wk, bk, qW_g, qb_g, b * 8 + jt);
    arrive(cB);
  }
  float4 pf[4];
  {
    const float* xsrc = x + (((long)b * NF_ + 0) * N_ + jt * 64) * D_;
#pragma unroll
    for (int i = 0; i < 4; ++i) {
      int ch = t + i * 512;
      pf[i] = *(const float4*)(xsrc + (ch >> 5) * 128 + (ch & 31) * 4);
    }
  }
  wait_for(cB, 8u);

  for (int it = 0; it < 17; ++it) {
    int f = (it == 0) ? 0 : it - 1;
    int wo = it > 0;
    // ================= phase A (all 256 blocks; per-batch tiles) =================
#pragma unroll
    for (int i = 0; i < 4; ++i) {
      int ch = t + i * 512;
      float* dst = sm.a.Xt + (ch >> 5) * 129 + (ch & 31) * 4;
      dst[0] = pf[i].x; dst[1] = pf[i].y; dst[2] = pf[i].z; dst[3] = pf[i].w;
    }
    sm.a.qWs[t] = gload(&qW_g[b * 1024 + t]);
    sm.a.qWs[512 + t] = gload(&qW_g[b * 1024 + 512 + t]);
    if (t < 8) sm.a.qbs[t] = gload(&qb_g[b * 8 + t]);
    __syncthreads();
    int r8 = t >> 3, p8 = t & 7;
    {
      const float* row = sm.a.Xt + r8 * 129 + p8 * 16;
      float s1 = 0.f, s2 = 0.f;
#pragma unroll
      for (int i = 0; i < 16; ++i) { float v = row[i]; s1 += v; s2 += v * v; }
      s1 += __shfl_down(s1, 1); s2 += __shfl_down(s2, 1);
      s1 += __shfl_down(s1, 2); s2 += __shfl_down(s2, 2);
      s1 += __shfl_down(s1, 4); s2 += __shfl_down(s2, 4);
      if (p8 == 0) { sm.a.rowsum[r8] = s1; sm.a.rowsum2[r8] = s2; }
    }
    __syncthreads();
    {
      float m = sm.a.rowsum[r8] * (1.f / 128.f);
      float var = sm.a.rowsum2[r8] * (1.f / 128.f) - m * m;
      float inv = rsqrtf(var + 1e-5f);
      float* row = sm.a.Xt + r8 * 129 + p8 * 16;
      const float* gg = gs + p8 * 16;
      const float* bb = bs_ + p8 * 16;
#pragma unroll
      for (int i = 0; i < 16; ++i) row[i] = (row[i] - m) * inv * gg[i] + bb[i];
    }
    __syncthreads();
    {
      int s = t >> 6, j = t & 63;
      const float* qq = sm.a.qWs + s * 128;
      const float* xr = sm.a.Xt + j * 129;
      float d = 0.f;
#pragma unroll
      for (int k = 0; k < 128; ++k) d += xr[k] * qq[k];
      sm.a.at[s * 64 + j] = (d + sm.a.qbs[s]) * SCALE_;
    }
    __syncthreads();
    if (t < 64) {
      float vals[8], mx = -1e30f;
#pragma unroll
      for (int s = 0; s < 8; ++s) { vals[s] = sm.a.at[s * 64 + t]; mx = fmaxf(mx, vals[s]); }
      float sum = 0.f;
#pragma unroll
      for (int s = 0; s < 8; ++s) { vals[s] = __expf(vals[s] - mx); sum += vals[s]; }
      float rr = 1.f / sum;
#pragma unroll
      for (int s = 0; s < 8; ++s) { vals[s] = vals[s] * rr + 1e-8f; sm.a.at[s * 64 + t] = vals[s]; }
      if (wo) {
#pragma unroll
        for (int s = 0; s < 8; ++s)
          out_attn[(((long)b * NF_ + f) * S_ + s) * N_ + jt * 64 + t] = vals[s];
      }
    }
    __syncthreads();
    {
      int w = t >> 6, lane = t & 63;
      float v = sm.a.at[w * 64 + lane];
#pragma unroll
      for (int off = 32; off; off >>= 1) v += __shfl_down(v, off);
      if (lane == 0) gstore(&S_part[(b * 16 + jt) * 8 + w], v);
    }
    {
      int k2 = t & 127, h = t >> 7;
      float u0 = 0.f, u1 = 0.f;
      const float* a0 = sm.a.at + h * 64;
      const float* a1 = sm.a.at + (h + 4) * 64;
#pragma unroll 8
      for (int j = 0; j < 64; ++j) {
        float xv = sm.a.Xt[j * 129 + k2];
        u0 += xv * a0[j]; u1 += xv * a1[j];
      }
      float* pp = P_part + (long)(b * 16 + jt) * 8 * 128;
      gstore(&pp[h * 128 + k2], u0);
      gstore(&pp[(h + 4) * 128 + k2], u1);
    }
    arrive(cA);  // all 16 blocks of batch b announce P/S partials
    if (it < 16) {  // prefetch next frame tile (f(it+1) == it) while others compute
      const float* xsrc = x + (((long)b * NF_ + it) * N_ + jt * 64) * D_;
#pragma unroll
      for (int i = 0; i < 4; ++i) {
        int ch = t + i * 512;
        pf[i] = *(const float4*)(xsrc + (ch >> 5) * 128 + (ch & 31) * 4);
      }
    }
    // ================= phase B (blocks jt<8: slot s=jt of batch b) =================
    if (isB) {
      wait_for(cA, 16u * (it + 1));
      SmemB& B = sm.b;
      int s = jt;
      // stage 1: reduce P (t<128) and S (t<16)
      if (t < 128) {
        float pa = 0.f;
#pragma unroll
        for (int j = 0; j < 16; ++j)
          pa += gload(&P_part[(long)((b * 16 + j) * 8 + s) * 128 + t]);
        B.Pk[t] = pa;
      }
      if (t < 16) {
        float sv = gload(&S_part[(b * 16 + t) * 8 + s]);
        sv += __shfl_down(sv, 8); sv += __shfl_down(sv, 4);
        sv += __shfl_down(sv, 2); sv += __shfl_down(sv, 1);
        if (t == 0) B.ssm = sv;
      }
      __syncthreads();
      // stage 2: upd = Wv@Pk/ss + bv (t<128); gh = Whh@hprev (t>=128 -> rows 0..383)
      if (t < 128) {
        float a = dot128f(Wv + t * 128, B.Pk, 0.f);
        B.upd[t] = a / B.ssm + bv[t];
      } else {
        int r = t - 128;
        B.gh[r] = dot128f(Whh + r * 128, slot_sh, bhh[r]);
      }
      __syncthreads();
      // stage 3: gi = Wih@upd (t<384)
      if (t < 384) B.gi[t] = dot128f(Wih + t * 128, B.upd, bih[t]);
      __syncthreads();
      // stage 4: gates -> hn
      if (t < 128) {
        float r = sigm(B.gi[t] + B.gh[t]);
        float z = sigm(B.gi[128 + t] + B.gh[128 + t]);
        float n = tanh_f(B.gi[256 + t] + r * B.gh[256 + t]);
        B.hn[t] = (1.f - z) * n + z * slot_sh[t];
      }
      // stage 5: LN_ff(hn) -> buf
      float m, inv;
      float hv = (t < 128) ? B.hn[t] : 0.f;  // stats128 syncs before reading
      stats128(hv, t, B.red, m, inv, 1e-5f);
      if (t < 128) B.buf[t] = (hv - m) * inv * g_ff[t] + be_ff[t];
      __syncthreads();
      // stage 6: hid = relu(W1@buf + b1)
      if (t < 128) B.hid[t] = fmaxf(dot128f(W1 + t * 128, B.buf, b1[t]), 0.f);
      __syncthreads();
      // stage 7: sn = hn + W2@hid + b2 -> slot_sh, out
      if (t < 128) {
        float ffv = dot128f(W2 + t * 128, B.hid, b2[t]);
        float sn = B.hn[t] + ffv;
        slot_sh[t] = sn;
        if (wo) out_slots[(((long)b * NF_ + f) * S_ + s) * D_ + t] = sn;
      }
      __syncthreads();
      // stages 8-10: next-frame q projection, then announce
      if (it < 16) {
        q_project(B, slot_sh, g_sl, be_sl, Wq, bq, Wk, bk, qW_g, qb_g, b * 8 + s);
        arrive(cB);
        wait_for(cB, 8u * (it + 2));
      }
    } else {
      if (it < 16) wait_for(cB, 8u * (it + 2));  // consumers of qW wait for the 8 producers
    }
  }
}

extern "C" void kernel_launch(void* const* d_in, const int* in_sizes, int n_in,
                              void* d_out, int out_size, void* d_ws, size_t ws_size,
                              hipStream_t stream) {
  const float* inputs     = (const float*)d_in[0];
  const float* slots_init = (const float*)d_in[1];
  const float* Wq  = (const float*)d_in[2];
  const float* bq  = (const float*)d_in[3];
  const float* Wk  = (const float*)d_in[4];
  const float* bk  = (const float*)d_in[5];
  const float* Wv  = (const float*)d_in[6];
  const float* bv  = (const float*)d_in[7];
  const float* W1  = (const float*)d_in[8];
  const float* b1  = (const float*)d_in[9];
  const float* W2  = (const float*)d_in[10];
  const float* b2  = (const float*)d_in[11];
  const float* Wih = (const float*)d_in[12];
  const float* Whh = (const float*)d_in[13];
  const float* bih = (const float*)d_in[14];
  const float* bhh = (const float*)d_in[15];
  const float* g_in  = (const float*)d_in[16];
  const float* be_in = (const float*)d_in[17];
  const float* g_sl  = (const float*)d_in[18];
  const float* be_sl = (const float*)d_in[19];
  const float* g_ff  = (const float*)d_in[20];
  const float* be_ff = (const float*)d_in[21];

  float* out_slots = (float*)d_out;
  float* out_attn  = out_slots + (size_t)B_ * NF_ * S_ * D_;

  char* ws = (char*)d_ws;
  unsigned* cntA = (unsigned*)ws;                    // 16 counters, 256 B apart (4 KB)
  unsigned* cntB = (unsigned*)(ws + 4096);           // 16 counters, 256 B apart (4 KB)
  float* qW_g    = (float*)(ws + 16384);             // 64 KB
  float* qb_g    = (float*)(ws + 16384 + 65536);     // 512 B
  float* P_part  = (float*)(ws + 16384 + 66048);     // 1 MB
  float* S_part  = (float*)(ws + 16384 + 66048 + 1048576);  // 8 KB

  hipMemsetAsync(d_ws, 0, 16384, stream);  // zero all counters (graph-capturable)

  slot_persist<<<NB, NT, 0, stream>>>(inputs, slots_init, Wq, bq, Wk, bk, Wv, bv,
      W1, b1, W2, b2, Wih, Whh, bih, bhh, g_in, be_in, g_sl, be_sl, g_ff, be_ff,
      out_slots, out_attn, cntA, cntB, qW_g, qb_g, P_part, S_part);
}